// Round 14
// baseline (291.371 us; speedup 1.0000x reference)
//
#include <hip/hip_runtime.h>
#include <hip/hip_fp16.h>

#define B_ 8
#define S_ 2048
#define D_ 1024
#define M_ (B_ * S_)
#define NCH 8
#define LN_EPS 1e-5f

typedef _Float16 f16;
typedef _Float16 half8 __attribute__((ext_vector_type(8)));
typedef _Float16 half4_t __attribute__((ext_vector_type(4)));
typedef float floatx4 __attribute__((ext_vector_type(4)));

__device__ __forceinline__ void gload_lds16(const void* g, void* l) {
  __builtin_amdgcn_global_load_lds((const __attribute__((address_space(1))) void*)g,
                                   (__attribute__((address_space(3))) void*)l, 16, 0, 0);
}

// T1: bijective XCD-chunk remap (requires total blocks % 8 == 0)
__device__ __forceinline__ void xcd_remap(int& bx, int& by, int& bz) {
  const int gx = gridDim.x, gy = gridDim.y;
  const int nb = gx * gy * (int)gridDim.z;
  int f = blockIdx.x + gx * (blockIdx.y + gy * blockIdx.z);
  const int cpx = nb >> 3;
  f = (f & 7) * cpx + (f >> 3);
  bx = f % gx;
  f /= gx;
  by = f % gy;
  bz = f / gy;
}

// ---------------- fp32 -> fp16 cast (vectorized, grid-stride) ----------------
__global__ void k_cvt(const float* __restrict__ src, f16* __restrict__ dst, int n4) {
  int stride = gridDim.x * blockDim.x;
  for (int i = blockIdx.x * blockDim.x + threadIdx.x; i < n4; i += stride) {
    float4 v = ((const float4*)src)[i];
    half4_t h;
    h.x = (f16)v.x; h.y = (f16)v.y; h.z = (f16)v.z; h.w = (f16)v.w;
    ((half4_t*)dst)[i] = h;
  }
}

// fused cast of the 3 weight matrices (1 launch instead of 3)
__global__ void k_cvtw(const float* __restrict__ a, const float* __restrict__ b,
                       const float* __restrict__ c, f16* __restrict__ dst) {
  const int n4 = D_ * D_ / 4;
  const int i = blockIdx.x * 256 + threadIdx.x;
  const int which = i / n4, off = i - which * n4;
  const float* s = which == 0 ? a : (which == 1 ? b : c);
  const float4 v = ((const float4*)s)[off];
  half4_t h;
  h.x = (f16)v.x; h.y = (f16)v.y; h.z = (f16)v.z; h.w = (f16)v.w;
  ((half4_t*)dst)[i] = h;
}

// ======= 256x256 8-wave GEMM main loop: 8-phase / 2-K-tile pair =======
// BK=64, dbuf LDS (128 KB). Snake quadrant order, register fragment reuse
// (24 ds_read_b128 / K-tile / wave). Counted vmcnt(4) only at P4/P8; tail
// VW4/VW2/VW0. One barrier per phase (WAR/RAW ledger verified rounds 12/13).
// T2: 16B-slot XOR swizzle (source pre-swizzled, reads XOR'd).
// SCL variant (PV): per-K-tile sclv half8 from LDS folded into A-fragments.
#define STG_A(tn, h, buf)                                                     \
  {                                                                           \
    const f16* g = aG + (size_t)(tn) * 64 + (size_t)(h) * 128 * K;            \
    f16* l = As + (buf) * 16384 + (h) * 8192 + lOff;                          \
    gload_lds16(g, l);                                                        \
    gload_lds16(g + (size_t)64 * K, l + 4096);                                \
  }
#define STG_B(tn, h, buf)                                                     \
  {                                                                           \
    const f16* g = bG + (size_t)(tn) * 64 + (size_t)(h) * 128 * K;            \
    f16* l = Bs + (buf) * 16384 + (h) * 8192 + lOff;                          \
    gload_lds16(g, l);                                                        \
    gload_lds16(g + (size_t)64 * K, l + 4096);                                \
  }

template <bool SCL>
__device__ __forceinline__ void gemm8_loop(
    const f16* aG, const f16* bG, f16* As, f16* Bs, const f16* Ss,
    const int K, const int lOff, const int wr, const int wc, const int fr,
    const int lg, const int fs0, const int fs1, floatx4 (&acc)[2][4][2][2]) {
  const int NT = K >> 6;
  const int NP = NT >> 1;

  // prologue: t0 {A0,B0,B1,A1} -> buf0, t1 {A0,B0} -> buf1 (12 loads)
  STG_A(0, 0, 0);
  STG_B(0, 0, 0);
  STG_B(0, 1, 0);
  STG_A(0, 1, 0);
  STG_A(1, 0, 1);
  STG_B(1, 0, 1);
  asm volatile("s_waitcnt vmcnt(4)" ::: "memory");
  __builtin_amdgcn_s_barrier();

  half8 af[4][2], bf0[2][2], bf1[2][2];
  half8 sclv0 = {}, sclv1 = {};
  (void)lg;

#define LDSCL(T)                                                              \
  if constexpr (SCL) {                                                        \
    const f16* sp = Ss + (T) * 64 + lg * 8;                                   \
    sclv0 = *(const half8*)sp;                                                \
    sclv1 = *(const half8*)(sp + 32);                                         \
  }
#define LDA(BUF, MH)                                                          \
  _Pragma("unroll") for (int m = 0; m < 4; ++m) {                             \
    const f16* Ac = As + (BUF) * 16384;                                       \
    const int ar = ((MH) * 128 + wr * 64 + m * 16 + fr) * 64;                 \
    af[m][0] = *(const half8*)(Ac + ar + fs0);                                \
    af[m][1] = *(const half8*)(Ac + ar + fs1);                                \
    if constexpr (SCL) {                                                      \
      af[m][0] = af[m][0] * sclv0;                                            \
      af[m][1] = af[m][1] * sclv1;                                            \
    }                                                                         \
  }
#define LDB(BUF, NH, DST)                                                     \
  _Pragma("unroll") for (int n = 0; n < 2; ++n) {                             \
    const f16* Bc = Bs + (BUF) * 16384;                                       \
    const int br = ((NH) * 128 + wc * 32 + n * 16 + fr) * 64;                 \
    DST[n][0] = *(const half8*)(Bc + br + fs0);                               \
    DST[n][1] = *(const half8*)(Bc + br + fs1);                               \
  }
#define PH(LOADS, MH, NH, BF, STAGE_STMT, WAIT_STMT)                          \
  {                                                                           \
    LOADS;                                                                    \
    STAGE_STMT;                                                               \
    __builtin_amdgcn_s_setprio(1);                                            \
    _Pragma("unroll") for (int m = 0; m < 4; ++m)                             \
      _Pragma("unroll") for (int n = 0; n < 2; ++n)                           \
        _Pragma("unroll") for (int kk = 0; kk < 2; ++kk)                      \
          acc[MH][m][NH][n] = __builtin_amdgcn_mfma_f32_16x16x32_f16(         \
              af[m][kk], BF[n][kk], acc[MH][m][NH][n], 0, 0, 0);              \
    __builtin_amdgcn_s_setprio(0);                                            \
    WAIT_STMT;                                                                \
    __builtin_amdgcn_s_barrier();                                             \
  }
#define VW4 asm volatile("s_waitcnt vmcnt(4)" ::: "memory")
#define VW2 asm volatile("s_waitcnt vmcnt(2)" ::: "memory")
#define VW0 asm volatile("s_waitcnt vmcnt(0)" ::: "memory")
#define NOW (void)0

  for (int p = 0; p < NP; ++p) {
    const int t0 = 2 * p;
    const bool mid = (t0 + 2 < NT);
    const bool nxt = (t0 + 3 < NT);
    const bool last = (p == NP - 1);

    // ---- tile t0 (buf0), snake quadrants ----
    PH(LDSCL(t0); LDA(0, 0); LDB(0, 0, bf0), 0, 0, bf0, STG_B(t0 + 1, 1, 1), NOW);
    PH(LDB(0, 1, bf1), 0, 1, bf1, STG_A(t0 + 1, 1, 1), NOW);
    PH(LDA(0, 1), 1, 1, bf1, if (mid) STG_A(t0 + 2, 0, 0), NOW);
    PH(NOW, 1, 0, bf0, if (mid) STG_B(t0 + 2, 0, 0), VW4);
    // ---- tile t0+1 (buf1) ----
    PH(LDSCL(t0 + 1); LDA(1, 0); LDB(1, 0, bf0), 0, 0, bf0,
       if (mid) STG_B(t0 + 2, 1, 0), if (last) { VW2; });
    PH(LDB(1, 1, bf1), 0, 1, bf1, if (mid) STG_A(t0 + 2, 1, 0),
       if (last) { VW0; });
    PH(LDA(1, 1), 1, 1, bf1, if (nxt) STG_A(t0 + 3, 0, 1), NOW);
    PH(NOW, 1, 0, bf0, if (nxt) STG_B(t0 + 3, 0, 1), if (!last) { VW4; });
  }
#undef PH
#undef LDA
#undef LDB
#undef LDSCL
#undef VW4
#undef VW2
#undef VW0
#undef NOW
}

// -------- QKV projection, bz-batched; bz==2 writes V TRANSPOSED to Vt --------
// bz==2 epilogue: 2-pass LDS transpose (reuses SM after final loop barrier):
// write acc+bias into T[256 cols][stride 136] (<=2-way bank alias), barrier,
// coalesced 16B stores of Vt[b][d][s] rows (256B runs per thread pair).
// Same fp32 bias-add + single f16 rounding as before -> bit-identical V.
__global__ __launch_bounds__(512, 2) void k_qkv8b(
    const f16* __restrict__ X, const f16* __restrict__ W,
    f16* __restrict__ Qh, f16* __restrict__ Kh, f16* __restrict__ Vt,
    const float* __restrict__ bq, const float* __restrict__ bk,
    const float* __restrict__ bv) {
  __shared__ f16 SM[4 * 256 * 64];  // 128 KB
  f16* As = SM;
  f16* Bs = SM + 2 * 256 * 64;
  int bx, by, bz;
  xcd_remap(bx, by, bz);
  const int K = D_;
  const int tid = threadIdx.x;
  const int wid = tid >> 6, lane = tid & 63;
  const int wr = wid >> 2, wc = wid & 3;
  const int fr = lane & 15, lg = lane >> 4;

  const float* bp = bz == 0 ? bq : (bz == 1 ? bk : bv);

  const f16* Ab = X + (size_t)by * 256 * K;
  const f16* Bb = W + (size_t)bz * D_ * D_ + (size_t)bx * 256 * K;
  const int srow = tid >> 3;
  const int sslot = (tid & 7) ^ (srow & 7);
  const f16* aG = Ab + (size_t)srow * K + sslot * 8;
  const f16* bG = Bb + (size_t)srow * K + sslot * 8;
  const int lOff = srow * 64 + (tid & 7) * 8;

  const int sx = lane & 7;
  const int fs0 = ((lg) ^ sx) * 8;
  const int fs1 = ((4 + lg) ^ sx) * 8;

  floatx4 acc[2][4][2][2] = {};
  gemm8_loop<false>(aG, bG, As, Bs, nullptr, K, lOff, wr, wc, fr, lg, fs0, fs1, acc);

  if (bz != 2) {
    f16* outp = bz == 0 ? Qh : Kh;
#pragma unroll
    for (int mh = 0; mh < 2; ++mh)
#pragma unroll
      for (int m = 0; m < 4; ++m) {
        const int row0 = by * 256 + mh * 128 + wr * 64 + m * 16 + lg * 4;
#pragma unroll
        for (int nh = 0; nh < 2; ++nh)
#pragma unroll
          for (int n = 0; n < 2; ++n) {
            const int col = bx * 256 + nh * 128 + wc * 32 + n * 16 + fr;
            const float bvv = bp[col];
#pragma unroll
            for (int r = 0; r < 4; ++r)
              outp[(size_t)(row0 + r) * D_ + col] = (f16)(acc[mh][m][nh][n][r] + bvv);
          }
      }
    return;
  }

  // bz == 2: transpose epilogue (after final loop barrier, SM is free)
  f16* T = SM;  // [256 cols][136]
  const int b = by >> 3;
  const int c = tid >> 1, hh = tid & 1;
#pragma unroll
  for (int mh = 0; mh < 2; ++mh) {
    // pass 1: acc -> T (transposed, +bias)
#pragma unroll
    for (int m = 0; m < 4; ++m) {
      const int lrow = wr * 64 + m * 16 + lg * 4;
#pragma unroll
      for (int nh = 0; nh < 2; ++nh)
#pragma unroll
        for (int n = 0; n < 2; ++n) {
          const int lcol = nh * 128 + wc * 32 + n * 16 + fr;
          const float bvv = bp[bx * 256 + lcol];
          half4_t h;
          h.x = (f16)(acc[mh][m][nh][n][0] + bvv);
          h.y = (f16)(acc[mh][m][nh][n][1] + bvv);
          h.z = (f16)(acc[mh][m][nh][n][2] + bvv);
          h.w = (f16)(acc[mh][m][nh][n][3] + bvv);
          *(half4_t*)(T + lcol * 136 + lrow) = h;
        }
    }
    __builtin_amdgcn_s_barrier();
    // pass 2: T -> Vt coalesced (thread pair covers one col's 128 rows)
    {
      f16* dst = Vt + ((size_t)b * D_ + bx * 256 + c) * S_ +
                 (by & 7) * 256 + mh * 128 + hh * 64;
      const f16* srcT = T + c * 136 + hh * 64;
#pragma unroll
      for (int k = 0; k < 8; ++k)
        *(half8*)(dst + k * 8) = *(const half8*)(srcT + k * 8);
    }
    __builtin_amdgcn_s_barrier();
  }
}

// -------- scores GEMM + fused column stats; stores P' = exp(s - m_tile) ------
__global__ __launch_bounds__(512, 2) void k_scores8(
    const f16* __restrict__ Q, const f16* __restrict__ Kx, f16* __restrict__ Sc,
    float* __restrict__ pm, float* __restrict__ pz) {
  __shared__ f16 SM[4 * 256 * 64];
  __shared__ float smax[2][256];
  __shared__ float ssum[2][256];
  f16* As = SM;
  f16* Bs = SM + 2 * 256 * 64;
  int bx, by, bz;
  xcd_remap(bx, by, bz);
  const int tid = threadIdx.x;
  const int wid = tid >> 6, lane = tid & 63;
  const int wr = wid >> 2, wc = wid & 3;
  const int fr = lane & 15, lg = lane >> 4;
  const int K = D_;

  const f16* Ab = Q + (size_t)bz * S_ * D_ + (size_t)by * 256 * K;
  const f16* Bb = Kx + (size_t)bz * S_ * D_ + (size_t)bx * 256 * K;
  const int srow = tid >> 3;
  const int sslot = (tid & 7) ^ (srow & 7);
  const f16* aG = Ab + (size_t)srow * K + sslot * 8;
  const f16* bG = Bb + (size_t)srow * K + sslot * 8;
  const int lOff = srow * 64 + (tid & 7) * 8;

  const int sx = lane & 7;
  const int fs0 = ((lg) ^ sx) * 8;
  const int fs1 = ((4 + lg) ^ sx) * 8;

  floatx4 acc[2][4][2][2] = {};
  gemm8_loop<false>(aG, bG, As, Bs, nullptr, K, lOff, wr, wc, fr, lg, fs0, fs1, acc);

  // per-thread stats over 32 rows per column group (f16-rounded values)
  float cmax[2][2], csum[2][2];
#pragma unroll
  for (int nh = 0; nh < 2; ++nh)
#pragma unroll
    for (int n = 0; n < 2; ++n) {
      float mx = -1e30f;
#pragma unroll
      for (int mh = 0; mh < 2; ++mh)
#pragma unroll
        for (int m = 0; m < 4; ++m)
#pragma unroll
          for (int r = 0; r < 4; ++r)
            mx = fmaxf(mx, (float)(f16)acc[mh][m][nh][n][r]);
      float zz = 0.f;
#pragma unroll
      for (int mh = 0; mh < 2; ++mh)
#pragma unroll
        for (int m = 0; m < 4; ++m)
#pragma unroll
          for (int r = 0; r < 4; ++r)
            zz += __expf((float)(f16)acc[mh][m][nh][n][r] - mx);
#pragma unroll
      for (int o = 16; o <= 32; o <<= 1) {
        const float om = __shfl_xor(mx, o);
        const float oz = __shfl_xor(zz, o);
        const float nm = fmaxf(mx, om);
        zz = zz * __expf(mx - nm) + oz * __expf(om - nm);
        mx = nm;
      }
      cmax[nh][n] = mx;
      csum[nh][n] = zz;
    }
  __syncthreads();
  if (lg == 0) {
#pragma unroll
    for (int nh = 0; nh < 2; ++nh)
#pragma unroll
      for (int n = 0; n < 2; ++n) {
        const int c = nh * 128 + wc * 32 + n * 16 + fr;
        smax[wr][c] = cmax[nh][n];
        ssum[wr][c] = csum[nh][n];
      }
  }
  __syncthreads();

  // tile max per column (broadcast to all threads)
  float mt[2][2];
#pragma unroll
  for (int nh = 0; nh < 2; ++nh)
#pragma unroll
    for (int n = 0; n < 2; ++n) {
      const int c = nh * 128 + wc * 32 + n * 16 + fr;
      mt[nh][n] = fmaxf(smax[0][c], smax[1][c]);
    }

  // store P' = exp(s_f16 - m_tile)
#pragma unroll
  for (int mh = 0; mh < 2; ++mh)
#pragma unroll
    for (int m = 0; m < 4; ++m) {
      const int row0 = by * 256 + mh * 128 + wr * 64 + m * 16 + lg * 4;
#pragma unroll
      for (int nh = 0; nh < 2; ++nh)
#pragma unroll
        for (int n = 0; n < 2; ++n) {
          const int col = bx * 256 + nh * 128 + wc * 32 + n * 16 + fr;
#pragma unroll
          for (int r = 0; r < 4; ++r)
            Sc[(size_t)bz * S_ * S_ + (size_t)(row0 + r) * S_ + col] =
                (f16)__expf((float)(f16)acc[mh][m][nh][n][r] - mt[nh][n]);
        }
    }

  if (wr == 0 && lg == 0) {
#pragma unroll
    for (int nh = 0; nh < 2; ++nh)
#pragma unroll
      for (int n = 0; n < 2; ++n) {
        const int c = nh * 128 + wc * 32 + n * 16 + fr;
        const float m0 = smax[0][c], m1 = smax[1][c];
        const float nm = fmaxf(m0, m1);
        const float zz = ssum[0][c] * __expf(m0 - nm) + ssum[1][c] * __expf(m1 - nm);
        const size_t o = ((size_t)bz * NCH + by) * S_ + bx * 256 + c;
        pm[o] = nm;
        pz[o] = zz;
      }
  }
}

// ------- combine tile stats -> per-(tile,col) scale sclh[t][b][j] (f16) ------
__global__ void k_combine(const float* __restrict__ pm, const float* __restrict__ pz,
                          f16* __restrict__ sclh) {
  const int b = blockIdx.y;
  const int j = blockIdx.x * 256 + threadIdx.x;
  float m = -1e30f;
#pragma unroll
  for (int ch = 0; ch < NCH; ++ch) m = fmaxf(m, pm[((size_t)b * NCH + ch) * S_ + j]);
  float z = 0.f;
#pragma unroll
  for (int ch = 0; ch < NCH; ++ch)
    z += pz[((size_t)b * NCH + ch) * S_ + j] * __expf(pm[((size_t)b * NCH + ch) * S_ + j] - m);
  const float csc = 1.0f / (z * 32.0f);  // fold /sqrt(D), D=1024
#pragma unroll
  for (int ch = 0; ch < NCH; ++ch)
    sclh[((size_t)ch * B_ + b) * S_ + j] =
        (f16)(__expf(pm[((size_t)b * NCH + ch) * S_ + j] - m) * csc);
}

// -------- PV GEMM with fused scale: selfatt = (P' .* scl) * Vt^T -------------
__global__ __launch_bounds__(512, 2) void k_pv8(
    const f16* __restrict__ P, const f16* __restrict__ Vt,
    const f16* __restrict__ sclh, f16* __restrict__ selfatt) {
  __shared__ f16 SM[4 * 256 * 64];
  __shared__ f16 Ss[2048];
  f16* As = SM;
  f16* Bs = SM + 2 * 256 * 64;
  int bx, by, bz;
  xcd_remap(bx, by, bz);
  const int K = S_;
  const int tid = threadIdx.x;
  const int wid = tid >> 6, lane = tid & 63;
  const int wr = wid >> 2, wc = wid & 3;
  const int fr = lane & 15, lg = lane >> 4;

  const f16* Ab = P + (size_t)bz * S_ * S_ + (size_t)by * 256 * K;
  const f16* Bb = Vt + (size_t)bz * D_ * S_ + (size_t)bx * 256 * K;
  const int srow = tid >> 3;
  const int sslot = (tid & 7) ^ (srow & 7);
  const f16* aG = Ab + (size_t)srow * K + sslot * 8;
  const f16* bG = Bb + (size_t)srow * K + sslot * 8;
  const int lOff = srow * 64 + (tid & 7) * 8;

  const int sx = lane & 7;
  const int fs0 = ((lg) ^ sx) * 8;
  const int fs1 = ((4 + lg) ^ sx) * 8;

  // stage scl row (4 KB) into LDS BEFORE the main-loop prologue stages so the
  // prologue vmcnt(4) guarantees it resident at the first phase.
  if (tid < 256)
    gload_lds16(sclh + ((size_t)by * B_ + bz) * S_ + tid * 8, Ss + tid * 8);

  floatx4 acc[2][4][2][2] = {};
  gemm8_loop<true>(aG, bG, As, Bs, Ss, K, lOff, wr, wc, fr, lg, fs0, fs1, acc);

#pragma unroll
  for (int mh = 0; mh < 2; ++mh)
#pragma unroll
    for (int m = 0; m < 4; ++m) {
      const int row0 = by * 256 + mh * 128 + wr * 64 + m * 16 + lg * 4;
#pragma unroll
      for (int nh = 0; nh < 2; ++nh)
#pragma unroll
        for (int n = 0; n < 2; ++n) {
          const int col = bx * 256 + nh * 128 + wc * 32 + n * 16 + fr;
#pragma unroll
          for (int r = 0; r < 4; ++r)
            selfatt[(size_t)(bz * S_ + row0 + r) * D_ + col] =
                (f16)acc[mh][m][nh][n][r];
        }
    }
}

// ------------- LayerNorm per row + partial mean-pool (deterministic) ---------
__global__ __launch_bounds__(256) void k_ln_pool(
    const f16* __restrict__ selfatt, const float* __restrict__ gamma,
    const float* __restrict__ beta, float* __restrict__ part) {
  __shared__ float lds[4 * 1024];
  const int tid = threadIdx.x, wid = tid >> 6, lane = tid & 63;
  const int row0 = blockIdx.x * 64 + wid * 16;
  float g[16], be[16], acc[16];
#pragma unroll
  for (int t = 0; t < 16; ++t) {
    g[t] = gamma[lane + 64 * t];
    be[t] = beta[lane + 64 * t];
    acc[t] = 0.f;
  }
  for (int r = 0; r < 16; ++r) {
    const f16* xp = selfatt + (size_t)(row0 + r) * D_ + lane;
    float x[16], sum = 0.f, sq = 0.f;
#pragma unroll
    for (int t = 0; t < 16; ++t) {
      x[t] = (float)xp[64 * t];
      sum += x[t];
      sq += x[t] * x[t];
    }
#pragma unroll
    for (int o = 32; o > 0; o >>= 1) {
      sum += __shfl_xor(sum, o);
      sq += __shfl_xor(sq, o);
    }
    const float mu = sum * (1.f / 1024.f);
    const float var = sq * (1.f / 1024.f) - mu * mu;
    const float rstd = rsqrtf(var + LN_EPS);
#pragma unroll
    for (int t = 0; t < 16; ++t) acc[t] += (x[t] - mu) * rstd * g[t] + be[t];
  }
#pragma unroll
  for (int t = 0; t < 16; ++t) lds[wid * 1024 + lane + 64 * t] = acc[t];
  __syncthreads();
#pragma unroll
  for (int c = 0; c < 4; ++c) {
    const int d = tid + 256 * c;
    const float s = lds[d] + lds[1024 + d] + lds[2048 + d] + lds[3072 + d];
    part[(size_t)blockIdx.x * 1024 + d] = s;
  }
}

__global__ void k_final(const float* __restrict__ part, float* __restrict__ out) {
  const int idx = blockIdx.x * 256 + threadIdx.x;
  const int b = idx >> 10, d = idx & 1023;
  float s = 0.f;
#pragma unroll
  for (int slot = 0; slot < 32; ++slot)
    s += part[((size_t)(b * 32 + slot)) * 1024 + d];
  out[idx] = s * (1.0f / S_);
}

// ---------------------------------------------------------------------------
extern "C" void kernel_launch(void* const* d_in, const int* in_sizes, int n_in,
                              void* d_out, int out_size, void* d_ws, size_t ws_size,
                              hipStream_t stream) {
  (void)in_sizes; (void)n_in; (void)out_size;
  const float* inp = (const float*)d_in[0];
  const float* Wq = (const float*)d_in[2];
  const float* bq = (const float*)d_in[3];
  const float* Wk = (const float*)d_in[4];
  const float* bk = (const float*)d_in[5];
  const float* Wv = (const float*)d_in[6];
  const float* bv = (const float*)d_in[7];
  const float* gamma = (const float*)d_in[8];
  const float* beta = (const float*)d_in[9];
  float* out = (float*)d_out;

  char* ws = (char*)d_ws;
  const size_t MB = 1024 * 1024;
  if (ws_size < 244 * MB) return;  // proven available in round 3

  f16* Xh = (f16*)(ws);                   // [0,32) X -> selfatt
  f16* Qh = (f16*)(ws + 32 * MB);         // [32,64)
  f16* Kh = (f16*)(ws + 64 * MB);         // [64,96)
  f16* Vt = (f16*)(ws + 128 * MB);        // [128,160) [B][D][S] (written by qkv)
  f16* Sc = (f16*)(ws + 160 * MB);        // [160,224) [B][S][S] P' = exp(s-mt)
  f16* Wh = (f16*)(ws + 224 * MB);        // [224,230) [3][D][D]
  float* pm = (float*)(ws + 230 * MB);    // 512 KB [B][NCH][S]
  float* pz = (float*)(ws + 231 * MB);    // 512 KB
  f16* sclh = (f16*)(ws + 232 * MB);      // 256 KB [NCH][B][S]
  float* part = (float*)(ws + 233 * MB);  // 1 MB [256][1024]
  f16* selfatt = Xh;

  k_cvt<<<2048, 256, 0, stream>>>(inp, Xh, M_ * D_ / 4);
  k_cvtw<<<3 * D_ * D_ / 4 / 256, 256, 0, stream>>>(Wq, Wk, Wv, Wh);

  // QKV projection: one dispatch, bz-batched; bz==2 writes Vt directly
  k_qkv8b<<<dim3(D_ / 256, M_ / 256, 3), 512, 0, stream>>>(
      Xh, Wh, Qh, Kh, Vt, bq, bk, bv);

  // scores: 8-phase GEMM + fused stats; stores P' = exp(s - m_tile)
  k_scores8<<<dim3(S_ / 256, S_ / 256, B_), 512, 0, stream>>>(Qh, Kh, Sc, pm, pz);
  k_combine<<<dim3(S_ / 256, B_), 256, 0, stream>>>(pm, pz, sclh);

  // PV with fused per-(tile,col) scale: no standalone pexp pass
  k_pv8<<<dim3(D_ / 256, S_ / 256, B_), 512, 0, stream>>>(Sc, Vt, sclh, selfatt);

  k_ln_pool<<<M_ / 64, 256, 0, stream>>>(selfatt, gamma, beta, part);
  k_final<<<(B_ * D_) / 256, 256, 0, stream>>>(part, out);
}

// Round 15
// 287.423 us; speedup vs baseline: 1.0137x; 1.0137x over previous
//
#include <hip/hip_runtime.h>
#include <hip/hip_fp16.h>

#define B_ 8
#define S_ 2048
#define D_ 1024
#define M_ (B_ * S_)
#define NCH 8
#define LN_EPS 1e-5f

typedef _Float16 f16;
typedef _Float16 half8 __attribute__((ext_vector_type(8)));
typedef _Float16 half4_t __attribute__((ext_vector_type(4)));
typedef float floatx4 __attribute__((ext_vector_type(4)));

__device__ __forceinline__ void gload_lds16(const void* g, void* l) {
  __builtin_amdgcn_global_load_lds((const __attribute__((address_space(1))) void*)g,
                                   (__attribute__((address_space(3))) void*)l, 16, 0, 0);
}

// T1: bijective XCD-chunk remap (requires total blocks % 8 == 0)
__device__ __forceinline__ void xcd_remap(int& bx, int& by, int& bz) {
  const int gx = gridDim.x, gy = gridDim.y;
  const int nb = gx * gy * (int)gridDim.z;
  int f = blockIdx.x + gx * (blockIdx.y + gy * blockIdx.z);
  const int cpx = nb >> 3;
  f = (f & 7) * cpx + (f >> 3);
  bx = f % gx;
  f /= gx;
  by = f % gy;
  bz = f / gy;
}

// ------- fused fp32->fp16 cast of X + Wq + Wk + Wv (single launch) ----------
__global__ void k_cvtall(const float* __restrict__ x, const float* __restrict__ wq,
                         const float* __restrict__ wk, const float* __restrict__ wv,
                         f16* __restrict__ Xh, f16* __restrict__ Wh) {
  const int n4x = M_ * D_ / 4;       // 4,194,304
  const int n4w = D_ * D_ / 4;       // 262,144
  const int total = n4x + 3 * n4w;
  const int stride = gridDim.x * blockDim.x;
  for (int i = blockIdx.x * blockDim.x + threadIdx.x; i < total; i += stride) {
    const float* s;
    f16* d;
    int off;
    if (i < n4x) {
      s = x; d = Xh; off = i;
    } else {
      const int j = i - n4x;
      const int which = j / n4w;
      off = j - which * n4w;
      s = which == 0 ? wq : (which == 1 ? wk : wv);
      d = Wh + (size_t)which * D_ * D_ / 4 * 4;
    }
    const float4 v = ((const float4*)s)[off];
    half4_t h;
    h.x = (f16)v.x; h.y = (f16)v.y; h.z = (f16)v.z; h.w = (f16)v.w;
    ((half4_t*)d)[off] = h;
  }
}

// ======= 256x256 8-wave GEMM main loop: 8-phase / 2-K-tile pair =======
// BK=64, dbuf LDS (128 KB). Snake quadrant order, register fragment reuse
// (24 ds_read_b128 / K-tile / wave). Counted vmcnt(4) only at P4/P8; tail
// VW4/VW2/VW0. One barrier per phase (WAR/RAW ledger verified rounds 12/13).
// T2: 16B-slot XOR swizzle (source pre-swizzled, reads XOR'd).
// SCL variant (PV): per-K-tile sclv half8 from LDS folded into A-fragments.
// NOTE (round 14 post-mortem): this structure is LDS-read-port-bound
// (~65 KB LDS traffic vs ~155 cyc MFMA per phase-pair) -> MfmaUtil ~40% is
// the HIP-source ceiling here; BK=32 and 32x32 MFMA both fail the arithmetic.
#define STG_A(tn, h, buf)                                                     \
  {                                                                           \
    const f16* g = aG + (size_t)(tn) * 64 + (size_t)(h) * 128 * K;            \
    f16* l = As + (buf) * 16384 + (h) * 8192 + lOff;                          \
    gload_lds16(g, l);                                                        \
    gload_lds16(g + (size_t)64 * K, l + 4096);                                \
  }
#define STG_B(tn, h, buf)                                                     \
  {                                                                           \
    const f16* g = bG + (size_t)(tn) * 64 + (size_t)(h) * 128 * K;            \
    f16* l = Bs + (buf) * 16384 + (h) * 8192 + lOff;                          \
    gload_lds16(g, l);                                                        \
    gload_lds16(g + (size_t)64 * K, l + 4096);                                \
  }

template <bool SCL>
__device__ __forceinline__ void gemm8_loop(
    const f16* aG, const f16* bG, f16* As, f16* Bs, const f16* Ss,
    const int K, const int lOff, const int wr, const int wc, const int fr,
    const int lg, const int fs0, const int fs1, floatx4 (&acc)[2][4][2][2]) {
  const int NT = K >> 6;
  const int NP = NT >> 1;

  // prologue: t0 {A0,B0,B1,A1} -> buf0, t1 {A0,B0} -> buf1 (12 loads)
  STG_A(0, 0, 0);
  STG_B(0, 0, 0);
  STG_B(0, 1, 0);
  STG_A(0, 1, 0);
  STG_A(1, 0, 1);
  STG_B(1, 0, 1);
  asm volatile("s_waitcnt vmcnt(4)" ::: "memory");
  __builtin_amdgcn_s_barrier();

  half8 af[4][2], bf0[2][2], bf1[2][2];
  half8 sclv0 = {}, sclv1 = {};
  (void)lg;

#define LDSCL(T)                                                              \
  if constexpr (SCL) {                                                        \
    const f16* sp = Ss + (T) * 64 + lg * 8;                                   \
    sclv0 = *(const half8*)sp;                                                \
    sclv1 = *(const half8*)(sp + 32);                                         \
  }
#define LDA(BUF, MH)                                                          \
  _Pragma("unroll") for (int m = 0; m < 4; ++m) {                             \
    const f16* Ac = As + (BUF) * 16384;                                       \
    const int ar = ((MH) * 128 + wr * 64 + m * 16 + fr) * 64;                 \
    af[m][0] = *(const half8*)(Ac + ar + fs0);                                \
    af[m][1] = *(const half8*)(Ac + ar + fs1);                                \
    if constexpr (SCL) {                                                      \
      af[m][0] = af[m][0] * sclv0;                                            \
      af[m][1] = af[m][1] * sclv1;                                            \
    }                                                                         \
  }
#define LDB(BUF, NH, DST)                                                     \
  _Pragma("unroll") for (int n = 0; n < 2; ++n) {                             \
    const f16* Bc = Bs + (BUF) * 16384;                                       \
    const int br = ((NH) * 128 + wc * 32 + n * 16 + fr) * 64;                 \
    DST[n][0] = *(const half8*)(Bc + br + fs0);                               \
    DST[n][1] = *(const half8*)(Bc + br + fs1);                               \
  }
#define PH(LOADS, MH, NH, BF, STAGE_STMT, WAIT_STMT)                          \
  {                                                                           \
    LOADS;                                                                    \
    STAGE_STMT;                                                               \
    __builtin_amdgcn_s_setprio(1);                                            \
    _Pragma("unroll") for (int m = 0; m < 4; ++m)                             \
      _Pragma("unroll") for (int n = 0; n < 2; ++n)                           \
        _Pragma("unroll") for (int kk = 0; kk < 2; ++kk)                      \
          acc[MH][m][NH][n] = __builtin_amdgcn_mfma_f32_16x16x32_f16(         \
              af[m][kk], BF[n][kk], acc[MH][m][NH][n], 0, 0, 0);              \
    __builtin_amdgcn_s_setprio(0);                                            \
    WAIT_STMT;                                                                \
    __builtin_amdgcn_s_barrier();                                             \
  }
#define VW4 asm volatile("s_waitcnt vmcnt(4)" ::: "memory")
#define VW2 asm volatile("s_waitcnt vmcnt(2)" ::: "memory")
#define VW0 asm volatile("s_waitcnt vmcnt(0)" ::: "memory")
#define NOW (void)0

  for (int p = 0; p < NP; ++p) {
    const int t0 = 2 * p;
    const bool mid = (t0 + 2 < NT);
    const bool nxt = (t0 + 3 < NT);
    const bool last = (p == NP - 1);

    // ---- tile t0 (buf0), snake quadrants ----
    PH(LDSCL(t0); LDA(0, 0); LDB(0, 0, bf0), 0, 0, bf0, STG_B(t0 + 1, 1, 1), NOW);
    PH(LDB(0, 1, bf1), 0, 1, bf1, STG_A(t0 + 1, 1, 1), NOW);
    PH(LDA(0, 1), 1, 1, bf1, if (mid) STG_A(t0 + 2, 0, 0), NOW);
    PH(NOW, 1, 0, bf0, if (mid) STG_B(t0 + 2, 0, 0), VW4);
    // ---- tile t0+1 (buf1) ----
    PH(LDSCL(t0 + 1); LDA(1, 0); LDB(1, 0, bf0), 0, 0, bf0,
       if (mid) STG_B(t0 + 2, 1, 0), if (last) { VW2; });
    PH(LDB(1, 1, bf1), 0, 1, bf1, if (mid) STG_A(t0 + 2, 1, 0),
       if (last) { VW0; });
    PH(LDA(1, 1), 1, 1, bf1, if (nxt) STG_A(t0 + 3, 0, 1), NOW);
    PH(NOW, 1, 0, bf0, if (nxt) STG_B(t0 + 3, 0, 1), if (!last) { VW4; });
  }
#undef PH
#undef LDA
#undef LDB
#undef LDSCL
#undef VW4
#undef VW2
#undef VW0
#undef NOW
}

// -------- QKV projection, bz-batched: one dispatch ---------------------------
__global__ __launch_bounds__(512, 2) void k_qkv8b(
    const f16* __restrict__ X, const f16* __restrict__ W,
    f16* __restrict__ Qh, f16* __restrict__ Kh, f16* __restrict__ Vh,
    const float* __restrict__ bq, const float* __restrict__ bk,
    const float* __restrict__ bv) {
  __shared__ f16 As[2 * 256 * 64];
  __shared__ f16 Bs[2 * 256 * 64];
  int bx, by, bz;
  xcd_remap(bx, by, bz);
  const int K = D_;
  const int tid = threadIdx.x;
  const int wid = tid >> 6, lane = tid & 63;
  const int wr = wid >> 2, wc = wid & 3;
  const int fr = lane & 15, lg = lane >> 4;

  f16* outp = bz == 0 ? Qh : (bz == 1 ? Kh : Vh);
  const float* bp = bz == 0 ? bq : (bz == 1 ? bk : bv);

  const f16* Ab = X + (size_t)by * 256 * K;
  const f16* Bb = W + (size_t)bz * D_ * D_ + (size_t)bx * 256 * K;
  const int srow = tid >> 3;
  const int sslot = (tid & 7) ^ (srow & 7);
  const f16* aG = Ab + (size_t)srow * K + sslot * 8;
  const f16* bG = Bb + (size_t)srow * K + sslot * 8;
  const int lOff = srow * 64 + (tid & 7) * 8;

  const int sx = lane & 7;
  const int fs0 = ((lg) ^ sx) * 8;
  const int fs1 = ((4 + lg) ^ sx) * 8;

  floatx4 acc[2][4][2][2] = {};
  gemm8_loop<false>(aG, bG, As, Bs, nullptr, K, lOff, wr, wc, fr, lg, fs0, fs1, acc);

#pragma unroll
  for (int mh = 0; mh < 2; ++mh)
#pragma unroll
    for (int m = 0; m < 4; ++m) {
      const int row0 = by * 256 + mh * 128 + wr * 64 + m * 16 + lg * 4;
#pragma unroll
      for (int nh = 0; nh < 2; ++nh)
#pragma unroll
        for (int n = 0; n < 2; ++n) {
          const int col = bx * 256 + nh * 128 + wc * 32 + n * 16 + fr;
          const float bvv = bp[col];
#pragma unroll
          for (int r = 0; r < 4; ++r)
            outp[(size_t)(row0 + r) * D_ + col] = (f16)(acc[mh][m][nh][n][r] + bvv);
        }
    }
}

// -------- scores GEMM + fused column stats; stores P' = exp(s - m_tile) ------
__global__ __launch_bounds__(512, 2) void k_scores8(
    const f16* __restrict__ Q, const f16* __restrict__ Kx, f16* __restrict__ Sc,
    float* __restrict__ pm, float* __restrict__ pz) {
  __shared__ f16 As[2 * 256 * 64];
  __shared__ f16 Bs[2 * 256 * 64];
  __shared__ float smax[2][256];
  __shared__ float ssum[2][256];
  int bx, by, bz;
  xcd_remap(bx, by, bz);
  const int tid = threadIdx.x;
  const int wid = tid >> 6, lane = tid & 63;
  const int wr = wid >> 2, wc = wid & 3;
  const int fr = lane & 15, lg = lane >> 4;
  const int K = D_;

  const f16* Ab = Q + (size_t)bz * S_ * D_ + (size_t)by * 256 * K;
  const f16* Bb = Kx + (size_t)bz * S_ * D_ + (size_t)bx * 256 * K;
  const int srow = tid >> 3;
  const int sslot = (tid & 7) ^ (srow & 7);
  const f16* aG = Ab + (size_t)srow * K + sslot * 8;
  const f16* bG = Bb + (size_t)srow * K + sslot * 8;
  const int lOff = srow * 64 + (tid & 7) * 8;

  const int sx = lane & 7;
  const int fs0 = ((lg) ^ sx) * 8;
  const int fs1 = ((4 + lg) ^ sx) * 8;

  floatx4 acc[2][4][2][2] = {};
  gemm8_loop<false>(aG, bG, As, Bs, nullptr, K, lOff, wr, wc, fr, lg, fs0, fs1, acc);

  // per-thread stats over 32 rows per column group (f16-rounded values)
  float cmax[2][2], csum[2][2];
#pragma unroll
  for (int nh = 0; nh < 2; ++nh)
#pragma unroll
    for (int n = 0; n < 2; ++n) {
      float mx = -1e30f;
#pragma unroll
      for (int mh = 0; mh < 2; ++mh)
#pragma unroll
        for (int m = 0; m < 4; ++m)
#pragma unroll
          for (int r = 0; r < 4; ++r)
            mx = fmaxf(mx, (float)(f16)acc[mh][m][nh][n][r]);
      float zz = 0.f;
#pragma unroll
      for (int mh = 0; mh < 2; ++mh)
#pragma unroll
        for (int m = 0; m < 4; ++m)
#pragma unroll
          for (int r = 0; r < 4; ++r)
            zz += __expf((float)(f16)acc[mh][m][nh][n][r] - mx);
#pragma unroll
      for (int o = 16; o <= 32; o <<= 1) {
        const float om = __shfl_xor(mx, o);
        const float oz = __shfl_xor(zz, o);
        const float nm = fmaxf(mx, om);
        zz = zz * __expf(mx - nm) + oz * __expf(om - nm);
        mx = nm;
      }
      cmax[nh][n] = mx;
      csum[nh][n] = zz;
    }
  __syncthreads();
  if (lg == 0) {
#pragma unroll
    for (int nh = 0; nh < 2; ++nh)
#pragma unroll
      for (int n = 0; n < 2; ++n) {
        const int c = nh * 128 + wc * 32 + n * 16 + fr;
        smax[wr][c] = cmax[nh][n];
        ssum[wr][c] = csum[nh][n];
      }
  }
  __syncthreads();

  // tile max per column (broadcast to all threads)
  float mt[2][2];
#pragma unroll
  for (int nh = 0; nh < 2; ++nh)
#pragma unroll
    for (int n = 0; n < 2; ++n) {
      const int c = nh * 128 + wc * 32 + n * 16 + fr;
      mt[nh][n] = fmaxf(smax[0][c], smax[1][c]);
    }

  // store P' = exp(s_f16 - m_tile)
#pragma unroll
  for (int mh = 0; mh < 2; ++mh)
#pragma unroll
    for (int m = 0; m < 4; ++m) {
      const int row0 = by * 256 + mh * 128 + wr * 64 + m * 16 + lg * 4;
#pragma unroll
      for (int nh = 0; nh < 2; ++nh)
#pragma unroll
        for (int n = 0; n < 2; ++n) {
          const int col = bx * 256 + nh * 128 + wc * 32 + n * 16 + fr;
#pragma unroll
          for (int r = 0; r < 4; ++r)
            Sc[(size_t)bz * S_ * S_ + (size_t)(row0 + r) * S_ + col] =
                (f16)__expf((float)(f16)acc[mh][m][nh][n][r] - mt[nh][n]);
        }
    }

  if (wr == 0 && lg == 0) {
#pragma unroll
    for (int nh = 0; nh < 2; ++nh)
#pragma unroll
      for (int n = 0; n < 2; ++n) {
        const int c = nh * 128 + wc * 32 + n * 16 + fr;
        const float m0 = smax[0][c], m1 = smax[1][c];
        const float nm = fmaxf(m0, m1);
        const float zz = ssum[0][c] * __expf(m0 - nm) + ssum[1][c] * __expf(m1 - nm);
        const size_t o = ((size_t)bz * NCH + by) * S_ + bx * 256 + c;
        pm[o] = nm;
        pz[o] = zz;
      }
  }
}

// ------- combine tile stats -> per-(tile,col) scale sclh[t][b][j] (f16) ------
__global__ void k_combine(const float* __restrict__ pm, const float* __restrict__ pz,
                          f16* __restrict__ sclh) {
  const int b = blockIdx.y;
  const int j = blockIdx.x * 256 + threadIdx.x;
  float m = -1e30f;
#pragma unroll
  for (int ch = 0; ch < NCH; ++ch) m = fmaxf(m, pm[((size_t)b * NCH + ch) * S_ + j]);
  float z = 0.f;
#pragma unroll
  for (int ch = 0; ch < NCH; ++ch)
    z += pz[((size_t)b * NCH + ch) * S_ + j] * __expf(pm[((size_t)b * NCH + ch) * S_ + j] - m);
  const float csc = 1.0f / (z * 32.0f);  // fold /sqrt(D), D=1024
#pragma unroll
  for (int ch = 0; ch < NCH; ++ch)
    sclh[((size_t)ch * B_ + b) * S_ + j] =
        (f16)(__expf(pm[((size_t)b * NCH + ch) * S_ + j] - m) * csc);
}

// -------- PV GEMM with fused scale: selfatt = (P' .* scl) * Vt^T -------------
__global__ __launch_bounds__(512, 2) void k_pv8(
    const f16* __restrict__ P, const f16* __restrict__ Vt,
    const f16* __restrict__ sclh, f16* __restrict__ selfatt) {
  __shared__ f16 As[2 * 256 * 64];
  __shared__ f16 Bs[2 * 256 * 64];
  __shared__ f16 Ss[2048];
  int bx, by, bz;
  xcd_remap(bx, by, bz);
  const int K = S_;
  const int tid = threadIdx.x;
  const int wid = tid >> 6, lane = tid & 63;
  const int wr = wid >> 2, wc = wid & 3;
  const int fr = lane & 15, lg = lane >> 4;

  const f16* Ab = P + (size_t)bz * S_ * S_ + (size_t)by * 256 * K;
  const f16* Bb = Vt + (size_t)bz * D_ * S_ + (size_t)bx * 256 * K;
  const int srow = tid >> 3;
  const int sslot = (tid & 7) ^ (srow & 7);
  const f16* aG = Ab + (size_t)srow * K + sslot * 8;
  const f16* bG = Bb + (size_t)srow * K + sslot * 8;
  const int lOff = srow * 64 + (tid & 7) * 8;

  const int sx = lane & 7;
  const int fs0 = ((lg) ^ sx) * 8;
  const int fs1 = ((4 + lg) ^ sx) * 8;

  // stage scl row (4 KB) into LDS BEFORE the main-loop prologue stages so the
  // prologue vmcnt(4) guarantees it resident at the first phase.
  if (tid < 256)
    gload_lds16(sclh + ((size_t)by * B_ + bz) * S_ + tid * 8, Ss + tid * 8);

  floatx4 acc[2][4][2][2] = {};
  gemm8_loop<true>(aG, bG, As, Bs, Ss, K, lOff, wr, wc, fr, lg, fs0, fs1, acc);

#pragma unroll
  for (int mh = 0; mh < 2; ++mh)
#pragma unroll
    for (int m = 0; m < 4; ++m) {
      const int row0 = by * 256 + mh * 128 + wr * 64 + m * 16 + lg * 4;
#pragma unroll
      for (int nh = 0; nh < 2; ++nh)
#pragma unroll
        for (int n = 0; n < 2; ++n) {
          const int col = bx * 256 + nh * 128 + wc * 32 + n * 16 + fr;
#pragma unroll
          for (int r = 0; r < 4; ++r)
            selfatt[(size_t)(bz * S_ + row0 + r) * D_ + col] =
                (f16)acc[mh][m][nh][n][r];
        }
    }
}

// ---------------- V[z*S+...][D] -> Vt[z][D][S] tiled transpose ----------------
__global__ void k_transpose(const f16* __restrict__ V, f16* __restrict__ Vt) {
  __shared__ f16 t[64][72];
  const int b = blockIdx.z;
  const int j0 = blockIdx.x * 64, d0 = blockIdx.y * 64;
  const int rr = threadIdx.x >> 4;
  const int cc = (threadIdx.x & 15) * 4;
#pragma unroll
  for (int p = 0; p < 4; ++p) {
    const int j = rr + p * 16;
    const half4_t v = *(const half4_t*)(V + ((size_t)b * S_ + j0 + j) * D_ + d0 + cc);
    *(half4_t*)&t[j][cc] = v;
  }
  __syncthreads();
#pragma unroll
  for (int p = 0; p < 4; ++p) {
    const int d = rr + p * 16;
    half4_t v;
    v.x = t[cc][d]; v.y = t[cc + 1][d]; v.z = t[cc + 2][d]; v.w = t[cc + 3][d];
    *(half4_t*)(Vt + ((size_t)b * D_ + d0 + d) * S_ + j0 + cc) = v;
  }
}

// ------------- LayerNorm per row + partial mean-pool (deterministic) ---------
__global__ __launch_bounds__(256) void k_ln_pool(
    const f16* __restrict__ selfatt, const float* __restrict__ gamma,
    const float* __restrict__ beta, float* __restrict__ part) {
  __shared__ float lds[4 * 1024];
  const int tid = threadIdx.x, wid = tid >> 6, lane = tid & 63;
  const int row0 = blockIdx.x * 64 + wid * 16;
  float g[16], be[16], acc[16];
#pragma unroll
  for (int t = 0; t < 16; ++t) {
    g[t] = gamma[lane + 64 * t];
    be[t] = beta[lane + 64 * t];
    acc[t] = 0.f;
  }
  for (int r = 0; r < 16; ++r) {
    const f16* xp = selfatt + (size_t)(row0 + r) * D_ + lane;
    float x[16], sum = 0.f, sq = 0.f;
#pragma unroll
    for (int t = 0; t < 16; ++t) {
      x[t] = (float)xp[64 * t];
      sum += x[t];
      sq += x[t] * x[t];
    }
#pragma unroll
    for (int o = 32; o > 0; o >>= 1) {
      sum += __shfl_xor(sum, o);
      sq += __shfl_xor(sq, o);
    }
    const float mu = sum * (1.f / 1024.f);
    const float var = sq * (1.f / 1024.f) - mu * mu;
    const float rstd = rsqrtf(var + LN_EPS);
#pragma unroll
    for (int t = 0; t < 16; ++t) acc[t] += (x[t] - mu) * rstd * g[t] + be[t];
  }
#pragma unroll
  for (int t = 0; t < 16; ++t) lds[wid * 1024 + lane + 64 * t] = acc[t];
  __syncthreads();
#pragma unroll
  for (int c = 0; c < 4; ++c) {
    const int d = tid + 256 * c;
    const float s = lds[d] + lds[1024 + d] + lds[2048 + d] + lds[3072 + d];
    part[(size_t)blockIdx.x * 1024 + d] = s;
  }
}

__global__ void k_final(const float* __restrict__ part, float* __restrict__ out) {
  const int idx = blockIdx.x * 256 + threadIdx.x;
  const int b = idx >> 10, d = idx & 1023;
  float s = 0.f;
#pragma unroll
  for (int slot = 0; slot < 32; ++slot)
    s += part[((size_t)(b * 32 + slot)) * 1024 + d];
  out[idx] = s * (1.0f / S_);
}

// ---------------------------------------------------------------------------
extern "C" void kernel_launch(void* const* d_in, const int* in_sizes, int n_in,
                              void* d_out, int out_size, void* d_ws, size_t ws_size,
                              hipStream_t stream) {
  (void)in_sizes; (void)n_in; (void)out_size;
  const float* inp = (const float*)d_in[0];
  const float* Wq = (const float*)d_in[2];
  const float* bq = (const float*)d_in[3];
  const float* Wk = (const float*)d_in[4];
  const float* bk = (const float*)d_in[5];
  const float* Wv = (const float*)d_in[6];
  const float* bv = (const float*)d_in[7];
  const float* gamma = (const float*)d_in[8];
  const float* beta = (const float*)d_in[9];
  float* out = (float*)d_out;

  char* ws = (char*)d_ws;
  const size_t MB = 1024 * 1024;
  if (ws_size < 244 * MB) return;  // proven available in round 3

  f16* Xh = (f16*)(ws);                   // [0,32) X -> selfatt
  f16* Qh = (f16*)(ws + 32 * MB);         // [32,64)
  f16* Kh = (f16*)(ws + 64 * MB);         // [64,96)
  f16* Vh = (f16*)(ws + 96 * MB);         // [96,128) dead after transpose
  f16* Vt = (f16*)(ws + 128 * MB);        // [128,160) [B][D][S]
  f16* Sc = (f16*)(ws + 160 * MB);        // [160,224) [B][S][S] P' = exp(s-mt)
  f16* Wh = (f16*)(ws + 224 * MB);        // [224,230) [3][D][D]
  float* pm = (float*)(ws + 230 * MB);    // 512 KB [B][NCH][S]
  float* pz = (float*)(ws + 231 * MB);    // 512 KB
  f16* sclh = (f16*)(ws + 232 * MB);      // 256 KB [NCH][B][S]
  float* part = (float*)(ws + 233 * MB);  // 1 MB [256][1024]
  f16* selfatt = Xh;

  k_cvtall<<<2048, 256, 0, stream>>>(inp, Wq, Wk, Wv, Xh, Wh);

  // QKV projection: one dispatch, bz-batched
  k_qkv8b<<<dim3(D_ / 256, M_ / 256, 3), 512, 0, stream>>>(
      Xh, Wh, Qh, Kh, Vh, bq, bk, bv);

  k_transpose<<<dim3(S_ / 64, D_ / 64, B_), 256, 0, stream>>>(Vh, Vt);

  // scores: 8-phase GEMM + fused stats; stores P' = exp(s - m_tile)
  k_scores8<<<dim3(S_ / 256, S_ / 256, B_), 512, 0, stream>>>(Qh, Kh, Sc, pm, pz);
  k_combine<<<dim3(S_ / 256, B_), 256, 0, stream>>>(pm, pz, sclh);

  // PV with fused per-(tile,col) scale: no standalone pexp pass
  k_pv8<<<dim3(D_ / 256, S_ / 256, B_), 512, 0, stream>>>(Sc, Vt, sclh, selfatt);

  k_ln_pool<<<M_ / 64, 256, 0, stream>>>(selfatt, gamma, beta, part);
  k_final<<<(B_ * D_) / 256, 256, 0, stream>>>(part, out);
}